// Round 9
// baseline (157.691 us; speedup 1.0000x reference)
//
#include <hip/hip_runtime.h>
#include <hip/hip_bf16.h>
#include <math.h>

#define NH   4
#define DH   16
#define CH   64
#define KNN  10
#define KS   4
#define NV   4096
#define NB   4
#define MHID 256
#define BN   (NB * NV)

// canonical param-buffer offsets (f32 elements)
#define P_LN1G  0
#define P_LN1B  64
#define P_LN2G  128
#define P_LN2B  192
#define P_WQKV  256
#define P_BQKV  12544
#define P_WPROJ 12736
#define P_BPROJ 16832
#define P_W1    16896
#define P_B1    33280
#define P_W2    33536
#define P_B2    49920
#define P_TOT   49984

#define N_ING  (BN * CH + NB * NV * 3 + P_TOT + BN)   // 1,164,096 (div by 4)
#define N_ING4 (N_ING / 4)                            // 291,024
#define N_PACK (16384 + 16384 + 12288)                // 45,056

typedef __hip_bfloat16 bf16;
typedef __attribute__((ext_vector_type(8))) short short8;
typedef __attribute__((ext_vector_type(4))) float float4a;
typedef unsigned long long ull;

__device__ __forceinline__ float b2f(bf16 x) { return __bfloat162float(x); }

__device__ __forceinline__ float cvt(const void* p, int i, int isbf) {
  return isbf ? b2f(((const bf16*)p)[i]) : ((const float*)p)[i];
}

// bf16 -> f32 is exactly a 16-bit left shift (same numerics as b2f)
__device__ __forceinline__ float us2f(unsigned short u) {
  return __uint_as_float(((unsigned)u) << 16);
}

__device__ __forceinline__ float4 cvt4(const void* p, int i, int isbf) {
  float4 r;
  if (isbf) {
    ushort4 u = *(const ushort4*)((const unsigned short*)p + i);
    r.x = us2f(u.x); r.y = us2f(u.y); r.z = us2f(u.z); r.w = us2f(u.w);
  } else {
    r = *(const float4*)((const float*)p + i);
  }
  return r;
}

__device__ __forceinline__ float wave_sum_f32(float v) {
#pragma unroll
  for (int m = 32; m >= 1; m >>= 1) v += __shfl_xor(v, m, 64);
  return v;
}

__device__ __forceinline__ int wave_sum_i32(int v) {
#pragma unroll
  for (int m = 32; m >= 1; m >>= 1) v += __shfl_xor(v, m, 64);
  return v;
}

// lexicographic wave-min over (hi, lo) pairs
__device__ __forceinline__ void wave_min_kv(unsigned& hi, unsigned& lo) {
#pragma unroll
  for (int m = 32; m >= 1; m >>= 1) {
    unsigned ohi = __shfl_xor(hi, m, 64);
    unsigned olo = __shfl_xor(lo, m, 64);
    if (ohi < hi || (ohi == hi && olo < lo)) { hi = ohi; lo = olo; }
  }
}

__device__ __forceinline__ float tanh_fast(float u) {
  float e = __expf(2.0f * u);
  return 1.0f - 2.0f / (e + 1.0f);
}

// identical d2 expression everywhere (exactness anchor)
__device__ __forceinline__ float d2f(float x, float y, float z,
                                     float qx, float qy, float qz) {
  float dx = x - qx, dy = y - qy, dz = z - qz;
  return dx * dx + dy * dy + dz * dz;
}

// branchless register top-K insert on (d2bits<<32)|idx keys.
__device__ __forceinline__ void knn_insert(ull* arr, ull key) {
  if (key < arr[KNN - 1]) {
#pragma unroll
    for (int t = 0; t < KNN; ++t) {
      ull a = arr[t];
      bool lt = key < a;
      ull mn = lt ? key : a;
      ull mx = lt ? a : key;
      arr[t] = mn;
      key = mx;
    }
  }
}

// ---------------- K0: fused detect + ingest(4-wide) + pack ----------------
// Verbatim R4 (best-measured): stages xcan, ccan, pcan, mcan + weight packs.
__global__ __launch_bounds__(256) void k_prep(
    const void* xin, const void* coords, const void* maskr,
    const void* ln1g, const void* ln1b, const void* ln2g, const void* ln2b,
    const void* wqkv, const void* bqkv, const void* wproj, const void* bproj,
    const void* w1, const void* b1, const void* w2, const void* b2,
    float* __restrict__ xcan, float* __restrict__ ccan,
    float* __restrict__ pcan, int* __restrict__ mcan,
    unsigned short* __restrict__ w1p, unsigned short* __restrict__ w2p,
    unsigned short* __restrict__ wqp, int* __restrict__ flags)
{
  __shared__ int sfl[2];
  const int tid = threadIdx.x;
  if (tid < 64) {
    const unsigned short* xu = (const unsigned short*)xin;
    const unsigned* mu = (const unsigned*)maskr;
    int c = 0;
#pragma unroll
    for (int k = 0; k < 4; ++k) {
      unsigned short w = xu[tid * 4 + k];
      int e = (w >> 7) & 0xFF;
      c += (e >= 100 && e <= 140);
    }
#pragma unroll
    for (int m = 32; m >= 1; m >>= 1) c += __shfl_xor(c, m, 64);
    unsigned big = (mu[tid] > 1u) ? 1u : 0u;
#pragma unroll
    for (int m = 32; m >= 1; m >>= 1) big |= __shfl_xor(big, m, 64);
    if (tid == 0) {
      sfl[0] = (c >= 205) ? 1 : 0;
      sfl[1] = big ? 1 : 0;
      if (blockIdx.x == 0) { flags[0] = sfl[0]; flags[1] = sfl[1]; }
    }
  }
  __syncthreads();
  const int isbf = sfl[0], m8 = sfl[1];

  int id = blockIdx.x * 256 + tid;
  if (id < N_ING4) {
    int e4 = id * 4;
    const int n0 = BN * CH, n1 = NB * NV * 3, n2 = P_TOT;
    if (e4 < n0) { *(float4*)&xcan[e4] = cvt4(xin, e4, isbf); return; }
    e4 -= n0;
    if (e4 < n1) { *(float4*)&ccan[e4] = cvt4(coords, e4, isbf); return; }
    e4 -= n1;
    if (e4 < n2) {
      // all region boundaries are multiples of 4 -> whole quad in one region
      const void* src; int off;
      if      (e4 < P_LN1B)  { src = ln1g;  off = e4 - P_LN1G; }
      else if (e4 < P_LN2G)  { src = ln1b;  off = e4 - P_LN1B; }
      else if (e4 < P_LN2B)  { src = ln2g;  off = e4 - P_LN2G; }
      else if (e4 < P_WQKV)  { src = ln2b;  off = e4 - P_LN2B; }
      else if (e4 < P_BQKV)  { src = wqkv;  off = e4 - P_WQKV; }
      else if (e4 < P_WPROJ) { src = bqkv;  off = e4 - P_BQKV; }
      else if (e4 < P_BPROJ) { src = wproj; off = e4 - P_WPROJ; }
      else if (e4 < P_W1)    { src = bproj; off = e4 - P_BPROJ; }
      else if (e4 < P_B1)    { src = w1;    off = e4 - P_W1; }
      else if (e4 < P_W2)    { src = b1;    off = e4 - P_B1; }
      else if (e4 < P_B2)    { src = w2;    off = e4 - P_W2; }
      else                   { src = b2;    off = e4 - P_B2; }
      *(float4*)&pcan[e4] = cvt4(src, off, isbf);
      return;
    }
    e4 -= n2;
    if (m8) {
      uchar4 u = *(const uchar4*)((const unsigned char*)maskr + e4);
      mcan[e4 + 0] = u.x != 0; mcan[e4 + 1] = u.y != 0;
      mcan[e4 + 2] = u.z != 0; mcan[e4 + 3] = u.w != 0;
    } else {
      int4 vv = *(const int4*)((const int*)maskr + e4);
      mcan[e4 + 0] = vv.x != 0; mcan[e4 + 1] = vv.y != 0;
      mcan[e4 + 2] = vv.z != 0; mcan[e4 + 3] = vv.w != 0;
    }
    return;
  }
  id -= N_ING4;
  // ---- pack (reads RAW weight inputs; B-frag layout for 16x16x32) ----
  if (id < 16384) {            // w1: K=64, N=256 -> nt 0..15, kh 0..1
    int j = id & 7, l = (id >> 3) & 63, kh = (id >> 9) & 1, nt = id >> 10;
    int k = kh * 32 + ((l >> 4) * 8) + j;
    int n = nt * 16 + (l & 15);
    w1p[id] = __bfloat16_as_ushort(__float2bfloat16(cvt(w1, k * MHID + n, isbf)));
    return;
  }
  id -= 16384;
  if (id < 16384) {            // w2: K=256, N=64 -> nt 0..3, kh 0..7
    int j = id & 7, l = (id >> 3) & 63, kh = (id >> 9) & 7, nt = id >> 12;
    int k = kh * 32 + ((l >> 4) * 8) + j;
    int n = nt * 16 + (l & 15);
    w2p[id] = __bfloat16_as_ushort(__float2bfloat16(cvt(w2, k * CH + n, isbf)));
    return;
  }
  id -= 16384;
  if (id < 12288) {            // wqkv: K=64, N=192 -> nt 0..11, kh 0..1
    int j = id & 7, l = (id >> 3) & 63, kh = (id >> 9) & 1, nt = id >> 10;
    int k = kh * 32 + ((l >> 4) * 8) + j;
    int n = nt * 16 + (l & 15);
    wqp[id] = __bfloat16_as_ushort(__float2bfloat16(cvt(wqkv, k * 192 + n, isbf)));
  }
}

// -------- K1: MERGED 4096-cell bin (blocks 0..3) + LN1/QKV (4..1027) ------
// Bin = R4's measured-fast LDS-atomic counting sort, at 256 threads
// (16 pts/thread; R5 proved this tail code correct). Host kernel is lnqkv:
// 1024 blocks, occupancy capped at 8 blocks/CU by waves — adding the 16.4KB
// cnt[] leaves 18.7KB/block, still 8 blocks/CU => zero occupancy cost (the
// R5 mistake was putting this LDS on 1265 prep blocks). Removes the 4-CU
// standalone bin launch (252 CUs idle) + one launch gap.
// pbin sorted by cell id (z-major) => a z-slab is ONE contiguous span.
#define XQS 72
__global__ __launch_bounds__(256) void k_mid(
    const float* __restrict__ ccan, const int* __restrict__ mcan,
    float4* __restrict__ pbin, unsigned* __restrict__ bstart,
    const float* __restrict__ x, const float* __restrict__ pcan,
    const unsigned short* __restrict__ wqp, float* __restrict__ qkv)
{
  __shared__ unsigned short xnb[16 * XQS];   // lnqkv blocks (2.25 KB)
  __shared__ unsigned cnt[NV];               // bin blocks (16 KB)
  __shared__ unsigned woff[4];
  const int tid = threadIdx.x;
  const int wave = tid >> 6, lane = tid & 63;

  if (blockIdx.x < NB) {
    // ---------------- counting-sort bin, one batch per block ----------------
    const int b = blockIdx.x;
    const float* cb = ccan + (size_t)b * NV * 3;
    const int* mb = mcan + b * NV;
    unsigned* st = bstart + (size_t)b * 4104;

#pragma unroll
    for (int k = 0; k < 16; ++k) cnt[tid + k * 256] = 0;
    __syncthreads();

    // count
#pragma unroll 1
    for (int k = 0; k < 16; ++k) {
      int j = tid + k * 256;
      if (mb[j]) {
        int cx = (int)cb[j * 3];     cx = cx > 15 ? 15 : cx;
        int cy = (int)cb[j * 3 + 1]; cy = cy > 15 ? 15 : cy;
        int cz = (int)cb[j * 3 + 2]; cz = cz > 15 ? 15 : cz;
        atomicAdd(&cnt[(cz << 8) + (cy << 4) + cx], 1u);
      }
    }
    __syncthreads();

    // exclusive scan over 4096 cells: 16 cells/thread + wave scan + cross-wave
    unsigned s[16], tot = 0;
#pragma unroll
    for (int t = 0; t < 16; ++t) { s[t] = cnt[tid * 16 + t]; tot += s[t]; }
    unsigned v = tot;
#pragma unroll
    for (int d = 1; d < 64; d <<= 1) {
      unsigned o = __shfl_up(v, d, 64);
      if (lane >= d) v += o;
    }
    if (lane == 63) woff[wave] = v;
    __syncthreads();
    unsigned wpre = 0;
    for (int w = 0; w < wave; ++w) wpre += woff[w];
    unsigned r = wpre + v - tot;   // exclusive prefix for this thread's cells
#pragma unroll
    for (int t = 0; t < 16; ++t) {
      cnt[tid * 16 + t] = r; st[tid * 16 + t] = r; r += s[t];
    }
    if (tid == 255) st[4096] = r;   // nvalid
    __syncthreads();

    // scatter (cnt now = per-cell cursor; intra-cell order irrelevant:
    // downstream selection is by (d2bits,idx) key)
#pragma unroll 1
    for (int k = 0; k < 16; ++k) {
      int j = tid + k * 256;
      if (mb[j]) {
        float xx = cb[j * 3], yy = cb[j * 3 + 1], zz = cb[j * 3 + 2];
        int cx = (int)xx; cx = cx > 15 ? 15 : cx;
        int cy = (int)yy; cy = cy > 15 ? 15 : cy;
        int cz = (int)zz; cz = cz > 15 ? 15 : cz;
        unsigned pos = atomicAdd(&cnt[(cz << 8) + (cy << 4) + cx], 1u);
        float4 q; q.x = xx; q.y = yy; q.z = zz; q.w = __int_as_float(j);
        pbin[(size_t)b * NV + pos] = q;
      }
    }
    return;
  }

  // ---------------- LN1 + QKV (MFMA, R4 verbatim) ----------------
  const int row0 = (blockIdx.x - NB) * 16;
  {
    const float gg = pcan[P_LN1G + lane], bb = pcan[P_LN1B + lane];
#pragma unroll
    for (int r = 0; r < 4; ++r) {
      int m = wave * 4 + r;
      float v = x[(size_t)(row0 + m) * CH + lane];
      float mn = wave_sum_f32(v) * (1.0f / 64.0f);
      float d = v - mn;
      float var = wave_sum_f32(d * d) * (1.0f / 64.0f);
      float rs = 1.0f / sqrtf(var + 1e-5f);
      xnb[m * XQS + lane] =
          __bfloat16_as_ushort(__float2bfloat16(d * rs * gg + bb));
    }
  }
  __syncthreads();

  const int q = lane >> 4, c = lane & 15;
  short8 a0 = *(const short8*)&xnb[c * XQS + q * 8];
  short8 a1 = *(const short8*)&xnb[c * XQS + 32 + q * 8];

#pragma unroll
  for (int t = 0; t < 3; ++t) {
    int nt = wave * 3 + t;
    short8 b0 = *(const short8*)&wqp[(size_t)((nt * 2 + 0) * 64 + lane) * 8];
    short8 b1 = *(const short8*)&wqp[(size_t)((nt * 2 + 1) * 64 + lane) * 8];
    float4a z = {0.f, 0.f, 0.f, 0.f};
    z = __builtin_amdgcn_mfma_f32_16x16x32_bf16(a0, b0, z, 0, 0, 0);
    z = __builtin_amdgcn_mfma_f32_16x16x32_bf16(a1, b1, z, 0, 0, 0);
    int n = nt * 16 + c;
    float bq = pcan[P_BQKV + n];
#pragma unroll
    for (int r = 0; r < 4; ++r) {
      int m = q * 4 + r;
      qkv[(size_t)(row0 + m) * 192 + n] = z[r] + bq;
    }
  }
}

// ---------------- K2: z-slab KNN, one wave per valid query ----------------
// R4 verbatim (best-measured): one-pass lane-parallel coalesced float4 scan
// + per-lane register top-10 + 10-round wave merge. Exactness: outside the
// slab |dz| > R => d2 > R^2; >= 10 keys wave-wide with d2 <= R^2 => done;
// else expand one layer per side and scan ONLY the new spans. Full range =>
// unconditionally exact. Merge order identical to lax.top_k.
__global__ __launch_bounds__(256) void k_knn4(
    const float4* __restrict__ pbin, const unsigned* __restrict__ bstart,
    int* __restrict__ nbr)
{
  const int wave = threadIdx.x >> 6, lane = threadIdx.x & 63;
  const int b = blockIdx.x >> 10;
  const int slot = (blockIdx.x & 1023) * 4 + wave;
  const unsigned* st = bstart + (size_t)b * 4104;
  const int nval = (int)st[4096];
  if (slot >= nval) return;
  const float4* gpt = pbin + (size_t)b * NV;

  const float4 me = gpt[slot];            // wave-uniform broadcast
  const float qx = me.x, qy = me.y, qz = me.z;
  const int qi = __float_as_int(me.w);
  int cz = (int)qz; cz = cz > 15 ? 15 : cz;

  ull arr[KNN];
#pragma unroll
  for (int t = 0; t < KNN; ++t) arr[t] = ~0ull;

  int R = 2;
  int zlo = cz - 2 < 0 ? 0 : cz - 2;
  int zhi = cz + 2 > 15 ? 15 : cz + 2;
  {
    const int s = (int)st[zlo << 8], e = (int)st[(zhi + 1) << 8];
    for (int i = s + lane; i < e; i += 64) {
      float4 p = gpt[i];
      float d2 = d2f(p.x, p.y, p.z, qx, qy, qz);
      knn_insert(arr, ((ull)__float_as_uint(d2) << 32) |
                      (unsigned)__float_as_int(p.w));
    }
  }

  for (;;) {
    const float RR = (float)(R * R);
    int c = 0;
#pragma unroll
    for (int t = 0; t < KNN; ++t) {
      float d = __uint_as_float((unsigned)(arr[t] >> 32));   // NaN -> false
      c += (d <= RR) ? 1 : 0;
    }
    c = wave_sum_i32(c);
    if (c >= KNN) break;
    if (zlo == 0 && zhi == 15) break;     // full range scanned: exact
    ++R;
    const int nzlo = cz - R < 0 ? 0 : cz - R;
    const int nzhi = cz + R > 15 ? 15 : cz + R;
    {   // new low-side span
      const int s = (int)st[nzlo << 8], e = (int)st[zlo << 8];
      for (int i = s + lane; i < e; i += 64) {
        float4 p = gpt[i];
        float d2 = d2f(p.x, p.y, p.z, qx, qy, qz);
        knn_insert(arr, ((ull)__float_as_uint(d2) << 32) |
                        (unsigned)__float_as_int(p.w));
      }
    }
    {   // new high-side span
      const int s = (int)st[(zhi + 1) << 8], e = (int)st[(nzhi + 1) << 8];
      for (int i = s + lane; i < e; i += 64) {
        float4 p = gpt[i];
        float d2 = d2f(p.x, p.y, p.z, qx, qy, qz);
        knn_insert(arr, ((ull)__float_as_uint(d2) << 32) |
                        (unsigned)__float_as_int(p.w));
      }
    }
    zlo = nzlo; zhi = nzhi;
  }

  unsigned myj = 0;
#pragma unroll 1
  for (int r = 0; r < KNN; ++r) {
    unsigned hi = (unsigned)(arr[0] >> 32);
    unsigned lo = (unsigned)(arr[0] & 0xffffffffu);
    wave_min_kv(hi, lo);
    const ull win = ((ull)hi << 32) | lo;
    if (arr[0] == win) {
#pragma unroll
      for (int t = 0; t < KNN - 1; ++t) arr[t] = arr[t + 1];
      arr[KNN - 1] = ~0ull;
    }
    if (lane == r) myj = lo;
  }
  const int row = (b << 12) | qi;
  if (lane < KNN) nbr[(size_t)row * KNN + lane] = (int)(myj & (NV - 1));
}

// ------ K3: FUSED attention + proj + residual + LN2 + MLP + residual ------
// (R4 verbatim)
#define XNS 72
#define GS  264
__global__ __launch_bounds__(256) void k_attn_mlp(
    const float* __restrict__ qkv, const int* __restrict__ nbr,
    const int* __restrict__ mcan, const float* __restrict__ xcan,
    const float* __restrict__ pcan,
    const unsigned short* __restrict__ w1p,
    const unsigned short* __restrict__ w2p,
    const int* __restrict__ flags, void* __restrict__ out)
{
  __shared__ float wp[CH * CH];          // 16 KB
  __shared__ float bp[CH];
  __shared__ float otile[16][CH];        // 4 KB attn head-concat output
  __shared__ float xtile[16][CH];        // 4 KB x after attn residual
  __shared__ float sc[4][NH][KNN];
  __shared__ float wsel[4][NH][KS];
  __shared__ int   isel[4][NH][KS];
  __shared__ int   nb[4][KNN];
  __shared__ float npen[4][KNN];
  __shared__ unsigned short xnb[16 * XNS];   // 2.25 KB
  __shared__ unsigned short gb[16 * GS];     // 8.25 KB
  const int tid = threadIdx.x;
  const int wave = tid >> 6, lane = tid & 63;
  const int row0 = blockIdx.x * 16;
  const int b = row0 / NV;               // 16-row tile never crosses batch

  {
    const float4* src = (const float4*)(pcan + P_WPROJ);
    float4* dst = (float4*)wp;
    for (int i = tid; i < CH * CH / 4; i += 256) dst[i] = src[i];
    if (tid < CH) bp[tid] = pcan[P_BPROJ + tid];
  }
  __syncthreads();

  // ---- attention: each wave its own 4 rows (wave-local LDS scratch) ----
#pragma unroll 1
  for (int r = 0; r < 4; ++r) {
    const int m = wave * 4 + r;
    const int row = row0 + m;
    if (mcan[row]) {                       // wave-uniform branch
      if (lane < KNN) {
        int j = nbr[(size_t)row * KNN + lane] & (NV - 1);
        nb[wave][lane] = j;
        npen[wave][lane] = mcan[b * NV + j] ? 0.0f : -1e9f;
      }
      __builtin_amdgcn_wave_barrier();
      if (lane < NH * KNN) {
        int h = lane / KNN, kk = lane % KNN;
        int j = nb[wave][kk];
        const float* qp = qkv + (size_t)row * 192 + h * DH;
        const float* kp = qkv + ((size_t)(b * NV + j)) * 192 + 64 + h * DH;
        float acc = 0.f;
#pragma unroll
        for (int d = 0; d < DH; ++d) acc += qp[d] * kp[d];
        sc[wave][h][kk] = acc * 0.25f + npen[wave][kk];
      }
      __builtin_amdgcn_wave_barrier();
      if (lane < NH) {
        int h = lane;
        float sv[KS]; int sj[KS];
        unsigned used = 0;
#pragma unroll
        for (int rr = 0; rr < KS; ++rr) {
          float best = -INFINITY; int bi = 0;
#pragma unroll
          for (int kk = 0; kk < KNN; ++kk) {
            float s = sc[wave][h][kk];
            if (!(used & (1u << kk)) && s > best) { best = s; bi = kk; }
          }
          used |= 1u << bi; sv[rr] = best; sj[rr] = bi;
        }
        float mx = sv[0];
        float e[KS], sum = 0.f;
#pragma unroll
        for (int rr = 0; rr < KS; ++rr) { e[rr] = expf(sv[rr] - mx); sum += e[rr]; }
        float inv = 1.0f / sum;
#pragma unroll
        for (int rr = 0; rr < KS; ++rr) {
          wsel[wave][h][rr] = e[rr] * inv;
          isel[wave][h][rr] = nb[wave][sj[rr]];
        }
      }
      __builtin_amdgcn_wave_barrier();
      {
        int h = lane >> 4, d = lane & 15;
        float o = 0.f;
#pragma unroll
        for (int rr = 0; rr < KS; ++rr) {
          int j = isel[wave][h][rr];
          o += wsel[wave][h][rr] *
               qkv[((size_t)(b * NV + j)) * 192 + 128 + h * DH + d];
        }
        otile[m][lane] = o;
      }
      __builtin_amdgcn_wave_barrier();
    }
  }

  // ---- proj + attn residual into xtile ----
#pragma unroll 1
  for (int r = 0; r < 4; ++r) {
    const int m = wave * 4 + r;
    const int row = row0 + m;
    float x = xcan[(size_t)row * CH + lane];
    if (mcan[row]) {
      float acc = bp[lane];
#pragma unroll 4
      for (int cc = 0; cc < CH; ++cc)
        acc = fmaf(otile[m][cc], wp[cc * CH + lane], acc);
      x += 0.5f * acc;
    }
    xtile[m][lane] = x;
  }

  // ---- LN2 ----
  {
    const float gg = pcan[P_LN2G + lane], bb2 = pcan[P_LN2B + lane];
#pragma unroll
    for (int r = 0; r < 4; ++r) {
      int m = wave * 4 + r;
      float v = xtile[m][lane];
      float mn = wave_sum_f32(v) * (1.0f / 64.0f);
      float d = v - mn;
      float var = wave_sum_f32(d * d) * (1.0f / 64.0f);
      float rs = 1.0f / sqrtf(var + 1e-5f);
      xnb[m * XNS + lane] =
          __bfloat16_as_ushort(__float2bfloat16(d * rs * gg + bb2));
    }
  }
  __syncthreads();   // xnb + xtile visible block-wide

  const int q = lane >> 4, c = lane & 15;
  short8 a0 = *(const short8*)&xnb[c * XNS + q * 8];
  short8 a1 = *(const short8*)&xnb[c * XNS + 32 + q * 8];

  // ---- fc1 ----
  float4a acc1[4];
#pragma unroll
  for (int t = 0; t < 4; ++t) {
    int nt = wave * 4 + t;
    short8 b0 = *(const short8*)&w1p[(size_t)((nt * 2 + 0) * 64 + lane) * 8];
    short8 b1 = *(const short8*)&w1p[(size_t)((nt * 2 + 1) * 64 + lane) * 8];
    float4a z = {0.f, 0.f, 0.f, 0.f};
    z = __builtin_amdgcn_mfma_f32_16x16x32_bf16(a0, b0, z, 0, 0, 0);
    z = __builtin_amdgcn_mfma_f32_16x16x32_bf16(a1, b1, z, 0, 0, 0);
    acc1[t] = z;
  }
#pragma unroll
  for (int t = 0; t < 4; ++t) {
    int n = (wave * 4 + t) * 16 + c;
    float bo = pcan[P_B1 + n];
#pragma unroll
    for (int r = 0; r < 4; ++r) {
      float h = acc1[t][r] + bo;
      float u = 0.7978845608028654f * (h + 0.044715f * h * h * h);
      float gv = 0.5f * h * (1.0f + tanh_fast(u));
      gb[(q * 4 + r) * GS + n] = __bfloat16_as_ushort(__float2bfloat16(gv));
    }
  }
  __syncthreads();

  // ---- fc2 + final residual (xtile) ----
  float4a o = {0.f, 0.f, 0.f, 0.f};
#pragma unroll
  for (int kh = 0; kh < 8; ++kh) {
    short8 ag = *(const short8*)&gb[c * GS + kh * 32 + q * 8];
    short8 bg = *(const short8*)&w2p[(size_t)((wave * 8 + kh) * 64 + lane) * 8];
    o = __builtin_amdgcn_mfma_f32_16x16x32_bf16(ag, bg, o, 0, 0, 0);
  }
  {
    int n = wave * 16 + c;
    float b2v = pcan[P_B2 + n];
    const int isbf = flags[0];
#pragma unroll
    for (int r = 0; r < 4; ++r) {
      int m = q * 4 + r;
      size_t idx = (size_t)(row0 + m) * CH + n;
      float val = 0.5f * (o[r] + b2v) + xtile[m][n];
      if (isbf) ((bf16*)out)[idx] = __float2bfloat16(val);
      else      ((float*)out)[idx] = val;
    }
  }
}

extern "C" void kernel_launch(void* const* d_in, const int* in_sizes, int n_in,
                              void* d_out, int out_size, void* d_ws, size_t ws_size,
                              hipStream_t stream)
{
  char* ws = (char*)d_ws;
  float* qkv   = (float*)(ws);
  float* xcan  = (float*)(ws + 16777216);
  float* ccan  = (float*)(ws + 20971520);
  float* pcan  = (float*)(ws + 21168128);
  int*   mcan  = (int*)  (ws + 21368064);
  int*   nbr   = (int*)  (ws + 21433600);
  int*   flags = (int*)  (ws + 22088960);
  unsigned short* w1p = (unsigned short*)(ws + 22089728);   // 32 KB
  unsigned short* w2p = (unsigned short*)(ws + 22122496);   // 32 KB
  unsigned short* wqp = (unsigned short*)(ws + 22155264);   // 24 KB
  float4*   pbin   = (float4*)  (ws + 22179840);            // 256 KB
  unsigned* bstart = (unsigned*)(ws + 22441984);            // 64 KB

  const int total = N_ING4 + N_PACK;
  k_prep<<<(total + 255) / 256, 256, 0, stream>>>(
      d_in[0], d_in[1], d_in[2], d_in[3], d_in[4], d_in[5], d_in[6],
      d_in[7], d_in[8], d_in[9], d_in[10], d_in[11], d_in[12], d_in[13], d_in[14],
      xcan, ccan, pcan, mcan, w1p, w2p, wqp, flags);
  k_mid<<<NB + BN / 16, 256, 0, stream>>>(ccan, mcan, pbin, bstart,
                                          xcan, pcan, wqp, qkv);
  k_knn4<<<NB * (NV / 4), 256, 0, stream>>>(pbin, bstart, nbr);
  k_attn_mlp<<<BN / 16, 256, 0, stream>>>(qkv, nbr, mcan, xcan, pcan,
                                          w1p, w2p, flags, d_out);
}

// Round 10
// 147.868 us; speedup vs baseline: 1.0664x; 1.0664x over previous
//
#include <hip/hip_runtime.h>
#include <hip/hip_bf16.h>
#include <math.h>

#define NH   4
#define DH   16
#define CH   64
#define KNN  10
#define KS   4
#define NV   4096
#define NB   4
#define MHID 256
#define BN   (NB * NV)

// canonical param-buffer offsets (f32 elements)
#define P_LN1G  0
#define P_LN1B  64
#define P_LN2G  128
#define P_LN2B  192
#define P_WQKV  256
#define P_BQKV  12544
#define P_WPROJ 12736
#define P_BPROJ 16832
#define P_W1    16896
#define P_B1    33280
#define P_W2    33536
#define P_B2    49920
#define P_TOT   49984

#define N_ING  (BN * CH + NB * NV * 3 + P_TOT + BN)   // 1,164,096 (div by 4)
#define N_ING4 (N_ING / 4)                            // 291,024
#define N_PACK (16384 + 16384 + 12288)                // 45,056

typedef __hip_bfloat16 bf16;
typedef __attribute__((ext_vector_type(8))) short short8;
typedef __attribute__((ext_vector_type(4))) float float4a;
typedef unsigned long long ull;

__device__ __forceinline__ float b2f(bf16 x) { return __bfloat162float(x); }

__device__ __forceinline__ float cvt(const void* p, int i, int isbf) {
  return isbf ? b2f(((const bf16*)p)[i]) : ((const float*)p)[i];
}

// bf16 -> f32 is exactly a 16-bit left shift (same numerics as b2f)
__device__ __forceinline__ float us2f(unsigned short u) {
  return __uint_as_float(((unsigned)u) << 16);
}

__device__ __forceinline__ float4 cvt4(const void* p, int i, int isbf) {
  float4 r;
  if (isbf) {
    ushort4 u = *(const ushort4*)((const unsigned short*)p + i);
    r.x = us2f(u.x); r.y = us2f(u.y); r.z = us2f(u.z); r.w = us2f(u.w);
  } else {
    r = *(const float4*)((const float*)p + i);
  }
  return r;
}

__device__ __forceinline__ float wave_sum_f32(float v) {
#pragma unroll
  for (int m = 32; m >= 1; m >>= 1) v += __shfl_xor(v, m, 64);
  return v;
}

__device__ __forceinline__ int wave_sum_i32(int v) {
#pragma unroll
  for (int m = 32; m >= 1; m >>= 1) v += __shfl_xor(v, m, 64);
  return v;
}

// lexicographic wave-min over (hi, lo) pairs
__device__ __forceinline__ void wave_min_kv(unsigned& hi, unsigned& lo) {
#pragma unroll
  for (int m = 32; m >= 1; m >>= 1) {
    unsigned ohi = __shfl_xor(hi, m, 64);
    unsigned olo = __shfl_xor(lo, m, 64);
    if (ohi < hi || (ohi == hi && olo < lo)) { hi = ohi; lo = olo; }
  }
}

__device__ __forceinline__ float tanh_fast(float u) {
  float e = __expf(2.0f * u);
  return 1.0f - 2.0f / (e + 1.0f);
}

// identical d2 expression everywhere (exactness anchor)
__device__ __forceinline__ float d2f(float x, float y, float z,
                                     float qx, float qy, float qz) {
  float dx = x - qx, dy = y - qy, dz = z - qz;
  return dx * dx + dy * dy + dz * dz;
}

// branchless register top-K insert on (d2bits<<32)|idx keys.
__device__ __forceinline__ void knn_insert(ull* arr, ull key) {
  if (key < arr[KNN - 1]) {
#pragma unroll
    for (int t = 0; t < KNN; ++t) {
      ull a = arr[t];
      bool lt = key < a;
      ull mn = lt ? key : a;
      ull mx = lt ? a : key;
      arr[t] = mn;
      key = mx;
    }
  }
}

// ---------------- K0: fused detect + ingest(4-wide) + pack ----------------
// Verbatim R4 (best-measured): stages xcan, ccan, pcan, mcan + weight packs.
__global__ __launch_bounds__(256) void k_prep(
    const void* xin, const void* coords, const void* maskr,
    const void* ln1g, const void* ln1b, const void* ln2g, const void* ln2b,
    const void* wqkv, const void* bqkv, const void* wproj, const void* bproj,
    const void* w1, const void* b1, const void* w2, const void* b2,
    float* __restrict__ xcan, float* __restrict__ ccan,
    float* __restrict__ pcan, int* __restrict__ mcan,
    unsigned short* __restrict__ w1p, unsigned short* __restrict__ w2p,
    unsigned short* __restrict__ wqp, int* __restrict__ flags)
{
  __shared__ int sfl[2];
  const int tid = threadIdx.x;
  if (tid < 64) {
    const unsigned short* xu = (const unsigned short*)xin;
    const unsigned* mu = (const unsigned*)maskr;
    int c = 0;
#pragma unroll
    for (int k = 0; k < 4; ++k) {
      unsigned short w = xu[tid * 4 + k];
      int e = (w >> 7) & 0xFF;
      c += (e >= 100 && e <= 140);
    }
#pragma unroll
    for (int m = 32; m >= 1; m >>= 1) c += __shfl_xor(c, m, 64);
    unsigned big = (mu[tid] > 1u) ? 1u : 0u;
#pragma unroll
    for (int m = 32; m >= 1; m >>= 1) big |= __shfl_xor(big, m, 64);
    if (tid == 0) {
      sfl[0] = (c >= 205) ? 1 : 0;
      sfl[1] = big ? 1 : 0;
      if (blockIdx.x == 0) { flags[0] = sfl[0]; flags[1] = sfl[1]; }
    }
  }
  __syncthreads();
  const int isbf = sfl[0], m8 = sfl[1];

  int id = blockIdx.x * 256 + tid;
  if (id < N_ING4) {
    int e4 = id * 4;
    const int n0 = BN * CH, n1 = NB * NV * 3, n2 = P_TOT;
    if (e4 < n0) { *(float4*)&xcan[e4] = cvt4(xin, e4, isbf); return; }
    e4 -= n0;
    if (e4 < n1) { *(float4*)&ccan[e4] = cvt4(coords, e4, isbf); return; }
    e4 -= n1;
    if (e4 < n2) {
      // all region boundaries are multiples of 4 -> whole quad in one region
      const void* src; int off;
      if      (e4 < P_LN1B)  { src = ln1g;  off = e4 - P_LN1G; }
      else if (e4 < P_LN2G)  { src = ln1b;  off = e4 - P_LN1B; }
      else if (e4 < P_LN2B)  { src = ln2g;  off = e4 - P_LN2G; }
      else if (e4 < P_WQKV)  { src = ln2b;  off = e4 - P_LN2B; }
      else if (e4 < P_BQKV)  { src = wqkv;  off = e4 - P_WQKV; }
      else if (e4 < P_WPROJ) { src = bqkv;  off = e4 - P_BQKV; }
      else if (e4 < P_BPROJ) { src = wproj; off = e4 - P_WPROJ; }
      else if (e4 < P_W1)    { src = bproj; off = e4 - P_BPROJ; }
      else if (e4 < P_B1)    { src = w1;    off = e4 - P_W1; }
      else if (e4 < P_W2)    { src = b1;    off = e4 - P_B1; }
      else if (e4 < P_B2)    { src = w2;    off = e4 - P_W2; }
      else                   { src = b2;    off = e4 - P_B2; }
      *(float4*)&pcan[e4] = cvt4(src, off, isbf);
      return;
    }
    e4 -= n2;
    if (m8) {
      uchar4 u = *(const uchar4*)((const unsigned char*)maskr + e4);
      mcan[e4 + 0] = u.x != 0; mcan[e4 + 1] = u.y != 0;
      mcan[e4 + 2] = u.z != 0; mcan[e4 + 3] = u.w != 0;
    } else {
      int4 vv = *(const int4*)((const int*)maskr + e4);
      mcan[e4 + 0] = vv.x != 0; mcan[e4 + 1] = vv.y != 0;
      mcan[e4 + 2] = vv.z != 0; mcan[e4 + 3] = vv.w != 0;
    }
    return;
  }
  id -= N_ING4;
  // ---- pack (reads RAW weight inputs; B-frag layout for 16x16x32) ----
  if (id < 16384) {            // w1: K=64, N=256 -> nt 0..15, kh 0..1
    int j = id & 7, l = (id >> 3) & 63, kh = (id >> 9) & 1, nt = id >> 10;
    int k = kh * 32 + ((l >> 4) * 8) + j;
    int n = nt * 16 + (l & 15);
    w1p[id] = __bfloat16_as_ushort(__float2bfloat16(cvt(w1, k * MHID + n, isbf)));
    return;
  }
  id -= 16384;
  if (id < 16384) {            // w2: K=256, N=64 -> nt 0..3, kh 0..7
    int j = id & 7, l = (id >> 3) & 63, kh = (id >> 9) & 7, nt = id >> 12;
    int k = kh * 32 + ((l >> 4) * 8) + j;
    int n = nt * 16 + (l & 15);
    w2p[id] = __bfloat16_as_ushort(__float2bfloat16(cvt(w2, k * CH + n, isbf)));
    return;
  }
  id -= 16384;
  if (id < 12288) {            // wqkv: K=64, N=192 -> nt 0..11, kh 0..1
    int j = id & 7, l = (id >> 3) & 63, kh = (id >> 9) & 1, nt = id >> 10;
    int k = kh * 32 + ((l >> 4) * 8) + j;
    int n = nt * 16 + (l & 15);
    wqp[id] = __bfloat16_as_ushort(__float2bfloat16(cvt(wqkv, k * 192 + n, isbf)));
  }
}

// -------- K1 (1024 thr): bin blocks 0..3 (R4's fast 1024-thread bin,
// VERBATIM) + LN1/QKV blocks 4..259 (64 rows each = 4 independent 16-row
// tiles; wave group wave>>2 owns a tile, wave&3 plays R4's wave role —
// identical math/order per row). Bin now truly hides under 256 lnqkv
// blocks (R9's mistake: 256-thread bin tail was 4x slower than R4's bin).
// Occupancy: 16 waves/CU either way; LDS ~25.7 KB/block, wave-limited.
#define XQS 72
__global__ __launch_bounds__(1024) void k_mid(
    const float* __restrict__ ccan, const int* __restrict__ mcan,
    float4* __restrict__ pbin, unsigned* __restrict__ bstart,
    const float* __restrict__ x, const float* __restrict__ pcan,
    const unsigned short* __restrict__ wqp, float* __restrict__ qkv)
{
  __shared__ unsigned cnt[NV];               // bin blocks (16 KB)
  __shared__ unsigned woff[16];
  __shared__ unsigned short xnb[64 * XQS];   // lnqkv blocks (9 KB)
  const int tid = threadIdx.x;
  const int wave = tid >> 6, lane = tid & 63;

  if (blockIdx.x < NB) {
    // ------------- R4 k_bin VERBATIM (1024 threads, 4 pts/thread) -------------
    const int b = blockIdx.x;
    const float* cb = ccan + (size_t)b * NV * 3;
    const int* mb = mcan + b * NV;
    unsigned* st = bstart + (size_t)b * 4104;

#pragma unroll
    for (int k = 0; k < 4; ++k) cnt[tid + k * 1024] = 0;
    __syncthreads();

#pragma unroll
    for (int k = 0; k < 4; ++k) {
      int j = tid + k * 1024;
      if (mb[j]) {
        int cx = (int)cb[j * 3];     cx = cx > 15 ? 15 : cx;
        int cy = (int)cb[j * 3 + 1]; cy = cy > 15 ? 15 : cy;
        int cz = (int)cb[j * 3 + 2]; cz = cz > 15 ? 15 : cz;
        atomicAdd(&cnt[(cz << 8) + (cy << 4) + cx], 1u);
      }
    }
    __syncthreads();

    // exclusive scan over 4096 cells: 4 cells/thread + wave scan
    unsigned s0 = cnt[tid * 4], s1 = cnt[tid * 4 + 1];
    unsigned s2 = cnt[tid * 4 + 2], s3 = cnt[tid * 4 + 3];
    unsigned tot = s0 + s1 + s2 + s3;
    unsigned v = tot;
#pragma unroll
    for (int d = 1; d < 64; d <<= 1) {
      unsigned o = __shfl_up(v, d, 64);
      if (lane >= d) v += o;
    }
    if (lane == 63) woff[wave] = v;
    __syncthreads();
    unsigned wpre = 0;
    for (int w = 0; w < wave; ++w) wpre += woff[w];
    unsigned r = wpre + v - tot;   // exclusive prefix for this thread's cells
    cnt[tid * 4]     = r; st[tid * 4]     = r; r += s0;
    cnt[tid * 4 + 1] = r; st[tid * 4 + 1] = r; r += s1;
    cnt[tid * 4 + 2] = r; st[tid * 4 + 2] = r; r += s2;
    cnt[tid * 4 + 3] = r; st[tid * 4 + 3] = r; r += s3;
    if (tid == 1023) st[4096] = r;   // nvalid
    __syncthreads();

    // scatter (cnt now = per-cell cursor; intra-cell order irrelevant:
    // downstream selection is by (d2bits,idx) key)
#pragma unroll
    for (int k = 0; k < 4; ++k) {
      int j = tid + k * 1024;
      if (mb[j]) {
        float xx = cb[j * 3], yy = cb[j * 3 + 1], zz = cb[j * 3 + 2];
        int cx = (int)xx; cx = cx > 15 ? 15 : cx;
        int cy = (int)yy; cy = cy > 15 ? 15 : cy;
        int cz = (int)zz; cz = cz > 15 ? 15 : cz;
        unsigned pos = atomicAdd(&cnt[(cz << 8) + (cy << 4) + cx], 1u);
        float4 q; q.x = xx; q.y = yy; q.z = zz; q.w = __int_as_float(j);
        pbin[(size_t)b * NV + pos] = q;
      }
    }
    return;
  }

  // ------------- LN1 + QKV: 4 tiles of 16 rows per 1024-thread block -------------
  const int tile = wave >> 2, wv4 = wave & 3;
  const int row0 = (blockIdx.x - NB) * 64 + tile * 16;
  unsigned short* xt = xnb + tile * 16 * XQS;
  {
    const float gg = pcan[P_LN1G + lane], bb = pcan[P_LN1B + lane];
#pragma unroll
    for (int r = 0; r < 4; ++r) {
      int m = wv4 * 4 + r;
      float v = x[(size_t)(row0 + m) * CH + lane];
      float mn = wave_sum_f32(v) * (1.0f / 64.0f);
      float d = v - mn;
      float var = wave_sum_f32(d * d) * (1.0f / 64.0f);
      float rs = 1.0f / sqrtf(var + 1e-5f);
      xt[m * XQS + lane] =
          __bfloat16_as_ushort(__float2bfloat16(d * rs * gg + bb));
    }
  }
  __syncthreads();

  const int q = lane >> 4, c = lane & 15;
  short8 a0 = *(const short8*)&xt[c * XQS + q * 8];
  short8 a1 = *(const short8*)&xt[c * XQS + 32 + q * 8];

#pragma unroll
  for (int t = 0; t < 3; ++t) {
    int nt = wv4 * 3 + t;
    short8 b0 = *(const short8*)&wqp[(size_t)((nt * 2 + 0) * 64 + lane) * 8];
    short8 b1 = *(const short8*)&wqp[(size_t)((nt * 2 + 1) * 64 + lane) * 8];
    float4a z = {0.f, 0.f, 0.f, 0.f};
    z = __builtin_amdgcn_mfma_f32_16x16x32_bf16(a0, b0, z, 0, 0, 0);
    z = __builtin_amdgcn_mfma_f32_16x16x32_bf16(a1, b1, z, 0, 0, 0);
    int n = nt * 16 + c;
    float bq = pcan[P_BQKV + n];
#pragma unroll
    for (int r = 0; r < 4; ++r) {
      int m = q * 4 + r;
      qkv[(size_t)(row0 + m) * 192 + n] = z[r] + bq;
    }
  }
}

// ---------------- K2: z-slab KNN, one wave per valid query ----------------
// R4 verbatim (best-measured).
__global__ __launch_bounds__(256) void k_knn4(
    const float4* __restrict__ pbin, const unsigned* __restrict__ bstart,
    int* __restrict__ nbr)
{
  const int wave = threadIdx.x >> 6, lane = threadIdx.x & 63;
  const int b = blockIdx.x >> 10;
  const int slot = (blockIdx.x & 1023) * 4 + wave;
  const unsigned* st = bstart + (size_t)b * 4104;
  const int nval = (int)st[4096];
  if (slot >= nval) return;
  const float4* gpt = pbin + (size_t)b * NV;

  const float4 me = gpt[slot];            // wave-uniform broadcast
  const float qx = me.x, qy = me.y, qz = me.z;
  const int qi = __float_as_int(me.w);
  int cz = (int)qz; cz = cz > 15 ? 15 : cz;

  ull arr[KNN];
#pragma unroll
  for (int t = 0; t < KNN; ++t) arr[t] = ~0ull;

  int R = 2;
  int zlo = cz - 2 < 0 ? 0 : cz - 2;
  int zhi = cz + 2 > 15 ? 15 : cz + 2;
  {
    const int s = (int)st[zlo << 8], e = (int)st[(zhi + 1) << 8];
    for (int i = s + lane; i < e; i += 64) {
      float4 p = gpt[i];
      float d2 = d2f(p.x, p.y, p.z, qx, qy, qz);
      knn_insert(arr, ((ull)__float_as_uint(d2) << 32) |
                      (unsigned)__float_as_int(p.w));
    }
  }

  for (;;) {
    const float RR = (float)(R * R);
    int c = 0;
#pragma unroll
    for (int t = 0; t < KNN; ++t) {
      float d = __uint_as_float((unsigned)(arr[t] >> 32));   // NaN -> false
      c += (d <= RR) ? 1 : 0;
    }
    c = wave_sum_i32(c);
    if (c >= KNN) break;
    if (zlo == 0 && zhi == 15) break;     // full range scanned: exact
    ++R;
    const int nzlo = cz - R < 0 ? 0 : cz - R;
    const int nzhi = cz + R > 15 ? 15 : cz + R;
    {   // new low-side span
      const int s = (int)st[nzlo << 8], e = (int)st[zlo << 8];
      for (int i = s + lane; i < e; i += 64) {
        float4 p = gpt[i];
        float d2 = d2f(p.x, p.y, p.z, qx, qy, qz);
        knn_insert(arr, ((ull)__float_as_uint(d2) << 32) |
                        (unsigned)__float_as_int(p.w));
      }
    }
    {   // new high-side span
      const int s = (int)st[(zhi + 1) << 8], e = (int)st[(nzhi + 1) << 8];
      for (int i = s + lane; i < e; i += 64) {
        float4 p = gpt[i];
        float d2 = d2f(p.x, p.y, p.z, qx, qy, qz);
        knn_insert(arr, ((ull)__float_as_uint(d2) << 32) |
                        (unsigned)__float_as_int(p.w));
      }
    }
    zlo = nzlo; zhi = nzhi;
  }

  unsigned myj = 0;
#pragma unroll 1
  for (int r = 0; r < KNN; ++r) {
    unsigned hi = (unsigned)(arr[0] >> 32);
    unsigned lo = (unsigned)(arr[0] & 0xffffffffu);
    wave_min_kv(hi, lo);
    const ull win = ((ull)hi << 32) | lo;
    if (arr[0] == win) {
#pragma unroll
      for (int t = 0; t < KNN - 1; ++t) arr[t] = arr[t + 1];
      arr[KNN - 1] = ~0ull;
    }
    if (lane == r) myj = lo;
  }
  const int row = (b << 12) | qi;
  if (lane < KNN) nbr[(size_t)row * KNN + lane] = (int)(myj & (NV - 1));
}

// ------ K3: FUSED attention + proj + residual + LN2 + MLP + residual ------
// (R4 verbatim)
#define XNS 72
#define GS  264
__global__ __launch_bounds__(256) void k_attn_mlp(
    const float* __restrict__ qkv, const int* __restrict__ nbr,
    const int* __restrict__ mcan, const float* __restrict__ xcan,
    const float* __restrict__ pcan,
    const unsigned short* __restrict__ w1p,
    const unsigned short* __restrict__ w2p,
    const int* __restrict__ flags, void* __restrict__ out)
{
  __shared__ float wp[CH * CH];          // 16 KB
  __shared__ float bp[CH];
  __shared__ float otile[16][CH];        // 4 KB attn head-concat output
  __shared__ float xtile[16][CH];        // 4 KB x after attn residual
  __shared__ float sc[4][NH][KNN];
  __shared__ float wsel[4][NH][KS];
  __shared__ int   isel[4][NH][KS];
  __shared__ int   nb[4][KNN];
  __shared__ float npen[4][KNN];
  __shared__ unsigned short xnb[16 * XNS];   // 2.25 KB
  __shared__ unsigned short gb[16 * GS];     // 8.25 KB
  const int tid = threadIdx.x;
  const int wave = tid >> 6, lane = tid & 63;
  const int row0 = blockIdx.x * 16;
  const int b = row0 / NV;               // 16-row tile never crosses batch

  {
    const float4* src = (const float4*)(pcan + P_WPROJ);
    float4* dst = (float4*)wp;
    for (int i = tid; i < CH * CH / 4; i += 256) dst[i] = src[i];
    if (tid < CH) bp[tid] = pcan[P_BPROJ + tid];
  }
  __syncthreads();

  // ---- attention: each wave its own 4 rows (wave-local LDS scratch) ----
#pragma unroll 1
  for (int r = 0; r < 4; ++r) {
    const int m = wave * 4 + r;
    const int row = row0 + m;
    if (mcan[row]) {                       // wave-uniform branch
      if (lane < KNN) {
        int j = nbr[(size_t)row * KNN + lane] & (NV - 1);
        nb[wave][lane] = j;
        npen[wave][lane] = mcan[b * NV + j] ? 0.0f : -1e9f;
      }
      __builtin_amdgcn_wave_barrier();
      if (lane < NH * KNN) {
        int h = lane / KNN, kk = lane % KNN;
        int j = nb[wave][kk];
        const float* qp = qkv + (size_t)row * 192 + h * DH;
        const float* kp = qkv + ((size_t)(b * NV + j)) * 192 + 64 + h * DH;
        float acc = 0.f;
#pragma unroll
        for (int d = 0; d < DH; ++d) acc += qp[d] * kp[d];
        sc[wave][h][kk] = acc * 0.25f + npen[wave][kk];
      }
      __builtin_amdgcn_wave_barrier();
      if (lane < NH) {
        int h = lane;
        float sv[KS]; int sj[KS];
        unsigned used = 0;
#pragma unroll
        for (int rr = 0; rr < KS; ++rr) {
          float best = -INFINITY; int bi = 0;
#pragma unroll
          for (int kk = 0; kk < KNN; ++kk) {
            float s = sc[wave][h][kk];
            if (!(used & (1u << kk)) && s > best) { best = s; bi = kk; }
          }
          used |= 1u << bi; sv[rr] = best; sj[rr] = bi;
        }
        float mx = sv[0];
        float e[KS], sum = 0.f;
#pragma unroll
        for (int rr = 0; rr < KS; ++rr) { e[rr] = expf(sv[rr] - mx); sum += e[rr]; }
        float inv = 1.0f / sum;
#pragma unroll
        for (int rr = 0; rr < KS; ++rr) {
          wsel[wave][h][rr] = e[rr] * inv;
          isel[wave][h][rr] = nb[wave][sj[rr]];
        }
      }
      __builtin_amdgcn_wave_barrier();
      {
        int h = lane >> 4, d = lane & 15;
        float o = 0.f;
#pragma unroll
        for (int rr = 0; rr < KS; ++rr) {
          int j = isel[wave][h][rr];
          o += wsel[wave][h][rr] *
               qkv[((size_t)(b * NV + j)) * 192 + 128 + h * DH + d];
        }
        otile[m][lane] = o;
      }
      __builtin_amdgcn_wave_barrier();
    }
  }

  // ---- proj + attn residual into xtile ----
#pragma unroll 1
  for (int r = 0; r < 4; ++r) {
    const int m = wave * 4 + r;
    const int row = row0 + m;
    float x = xcan[(size_t)row * CH + lane];
    if (mcan[row]) {
      float acc = bp[lane];
#pragma unroll 4
      for (int cc = 0; cc < CH; ++cc)
        acc = fmaf(otile[m][cc], wp[cc * CH + lane], acc);
      x += 0.5f * acc;
    }
    xtile[m][lane] = x;
  }

  // ---- LN2 ----
  {
    const float gg = pcan[P_LN2G + lane], bb2 = pcan[P_LN2B + lane];
#pragma unroll
    for (int r = 0; r < 4; ++r) {
      int m = wave * 4 + r;
      float v = xtile[m][lane];
      float mn = wave_sum_f32(v) * (1.0f / 64.0f);
      float d = v - mn;
      float var = wave_sum_f32(d * d) * (1.0f / 64.0f);
      float rs = 1.0f / sqrtf(var + 1e-5f);
      xnb[m * XNS + lane] =
          __bfloat16_as_ushort(__float2bfloat16(d * rs * gg + bb2));
    }
  }
  __syncthreads();   // xnb + xtile visible block-wide

  const int q = lane >> 4, c = lane & 15;
  short8 a0 = *(const short8*)&xnb[c * XNS + q * 8];
  short8 a1 = *(const short8*)&xnb[c * XNS + 32 + q * 8];

  // ---- fc1 ----
  float4a acc1[4];
#pragma unroll
  for (int t = 0; t < 4; ++t) {
    int nt = wave * 4 + t;
    short8 b0 = *(const short8*)&w1p[(size_t)((nt * 2 + 0) * 64 + lane) * 8];
    short8 b1 = *(const short8*)&w1p[(size_t)((nt * 2 + 1) * 64 + lane) * 8];
    float4a z = {0.f, 0.f, 0.f, 0.f};
    z = __builtin_amdgcn_mfma_f32_16x16x32_bf16(a0, b0, z, 0, 0, 0);
    z = __builtin_amdgcn_mfma_f32_16x16x32_bf16(a1, b1, z, 0, 0, 0);
    acc1[t] = z;
  }
#pragma unroll
  for (int t = 0; t < 4; ++t) {
    int n = (wave * 4 + t) * 16 + c;
    float bo = pcan[P_B1 + n];
#pragma unroll
    for (int r = 0; r < 4; ++r) {
      float h = acc1[t][r] + bo;
      float u = 0.7978845608028654f * (h + 0.044715f * h * h * h);
      float gv = 0.5f * h * (1.0f + tanh_fast(u));
      gb[(q * 4 + r) * GS + n] = __bfloat16_as_ushort(__float2bfloat16(gv));
    }
  }
  __syncthreads();

  // ---- fc2 + final residual (xtile) ----
  float4a o = {0.f, 0.f, 0.f, 0.f};
#pragma unroll
  for (int kh = 0; kh < 8; ++kh) {
    short8 ag = *(const short8*)&gb[c * GS + kh * 32 + q * 8];
    short8 bg = *(const short8*)&w2p[(size_t)((wave * 8 + kh) * 64 + lane) * 8];
    o = __builtin_amdgcn_mfma_f32_16x16x32_bf16(ag, bg, o, 0, 0, 0);
  }
  {
    int n = wave * 16 + c;
    float b2v = pcan[P_B2 + n];
    const int isbf = flags[0];
#pragma unroll
    for (int r = 0; r < 4; ++r) {
      int m = q * 4 + r;
      size_t idx = (size_t)(row0 + m) * CH + n;
      float val = 0.5f * (o[r] + b2v) + xtile[m][n];
      if (isbf) ((bf16*)out)[idx] = __float2bfloat16(val);
      else      ((float*)out)[idx] = val;
    }
  }
}

extern "C" void kernel_launch(void* const* d_in, const int* in_sizes, int n_in,
                              void* d_out, int out_size, void* d_ws, size_t ws_size,
                              hipStream_t stream)
{
  char* ws = (char*)d_ws;
  float* qkv   = (float*)(ws);
  float* xcan  = (float*)(ws + 16777216);
  float* ccan  = (float*)(ws + 20971520);
  float* pcan  = (float*)(ws + 21168128);
  int*   mcan  = (int*)  (ws + 21368064);
  int*   nbr   = (int*)  (ws + 21433600);
  int*   flags = (int*)  (ws + 22088960);
  unsigned short* w1p = (unsigned short*)(ws + 22089728);   // 32 KB
  unsigned short* w2p = (unsigned short*)(ws + 22122496);   // 32 KB
  unsigned short* wqp = (unsigned short*)(ws + 22155264);   // 24 KB
  float4*   pbin   = (float4*)  (ws + 22179840);            // 256 KB
  unsigned* bstart = (unsigned*)(ws + 22441984);            // 64 KB

  const int total = N_ING4 + N_PACK;
  k_prep<<<(total + 255) / 256, 256, 0, stream>>>(
      d_in[0], d_in[1], d_in[2], d_in[3], d_in[4], d_in[5], d_in[6],
      d_in[7], d_in[8], d_in[9], d_in[10], d_in[11], d_in[12], d_in[13], d_in[14],
      xcan, ccan, pcan, mcan, w1p, w2p, wqp, flags);
  k_mid<<<NB + BN / 64, 1024, 0, stream>>>(ccan, mcan, pbin, bstart,
                                           xcan, pcan, wqp, qkv);
  k_knn4<<<NB * (NV / 4), 256, 0, stream>>>(pbin, bstart, nbr);
  k_attn_mlp<<<BN / 16, 256, 0, stream>>>(qkv, nbr, mcan, xcan, pcan,
                                          w1p, w2p, flags, d_out);
}